// Round 6
// baseline (581.258 us; speedup 1.0000x reference)
//
#include <hip/hip_runtime.h>

typedef _Float16 half_t;
typedef __attribute__((ext_vector_type(8))) _Float16 half8;
typedef __attribute__((ext_vector_type(4))) _Float16 half4;
typedef __attribute__((ext_vector_type(4))) float float4v;

#define LN_EPS 1e-5f
#define QK_SCALE 0.17677669529663687f   // 32^-0.5

static __device__ __forceinline__ float4v mfma16(half8 a, half8 b, float4v c) {
    return __builtin_amdgcn_mfma_f32_16x16x32_f16(a, b, c, 0, 0, 0);
}

// 512B rows, XOR key (row>>1)&7
static __device__ __forceinline__ int swzA(int row, int colByte) {
    return row * 512 + ((((colByte >> 4) ^ ((row >> 1) & 7)) << 4) | (colByte & 15));
}
// 64B rows, XOR key (row>>1)&3
static __device__ __forceinline__ int swzB(int row, int colByte) {
    return row * 64 + ((((colByte >> 4) ^ ((row >> 1) & 3)) << 4) | (colByte & 15));
}
// 128B rows, XOR key row&7 (vT slots: 32 rows x 128B)
static __device__ __forceinline__ int swzC(int row, int colByte) {
    return row * 128 + ((((colByte >> 4) ^ (row & 7)) << 4) | (colByte & 15));
}

static __device__ void ln_relu16(float* h, const float* __restrict__ g, const float* __restrict__ b) {
    float m = 0.f;
    for (int j = 0; j < 16; ++j) m += h[j];
    m *= (1.0f / 16.0f);
    float v = 0.f;
    for (int j = 0; j < 16; ++j) { float d = h[j] - m; v += d * d; }
    v *= (1.0f / 16.0f);
    float rs = rsqrtf(v + LN_EPS);
    for (int j = 0; j < 16; ++j) {
        float t = (h[j] - m) * rs * g[j] + b[j];
        h[j] = t > 0.f ? t : 0.f;
    }
}

// ---------------------------------------------------------------------------
// prep: weight transpose+fp16, pos-bias MLP, rel-bias table rbp[h][row][m][tj]
// ---------------------------------------------------------------------------
__global__ void prep_kernel(
    const float* __restrict__ qkv_w,   // [256,768]
    const float* __restrict__ proj_w,  // [256,256]
    const float* __restrict__ biases,  // [225,2]
    const float* __restrict__ pos_w, const float* __restrict__ pos_b,
    const float* __restrict__ ln1_g, const float* __restrict__ ln1_b,
    const float* __restrict__ fc1_w, const float* __restrict__ fc1_b,
    const float* __restrict__ ln2_g, const float* __restrict__ ln2_b,
    const float* __restrict__ fc2_w, const float* __restrict__ fc2_b,
    const float* __restrict__ ln3_g, const float* __restrict__ ln3_b,
    const float* __restrict__ fc3_w, const float* __restrict__ fc3_b,
    const int* __restrict__ rel_idx,   // [64,64]
    half_t* __restrict__ wqkvT,        // [768,256]
    half_t* __restrict__ wprojT,       // [256,256]
    float* __restrict__ rbp)           // [8][64][16][4]
{
    __shared__ float tile[64][65];
    __shared__ float pos_s[225][8];
    const int t = blockIdx.x;
    const int tid = threadIdx.x;

    if (t < 64) {
        const float* src; half_t* dst; int ncols, rg, cg;
        if (t < 48) { src = qkv_w;  dst = wqkvT;  ncols = 768; rg = t / 12;      cg = t % 12; }
        else        { src = proj_w; dst = wprojT; ncols = 256; rg = (t-48) >> 2; cg = (t-48) & 3; }
        const int r0 = tid >> 6, c = tid & 63;
        for (int i = 0; i < 16; ++i) {
            int r = i * 4 + r0;
            tile[r][c] = src[(rg * 64 + r) * ncols + cg * 64 + c];
        }
        __syncthreads();
        for (int i = 0; i < 16; ++i) {
            int r = i * 4 + r0;
            dst[(cg * 64 + r) * 256 + rg * 64 + c] = (half_t)tile[c][r];
        }
    } else {
        if (tid < 225) {
            float h[16], h2[16];
            float b0 = biases[tid * 2], b1 = biases[tid * 2 + 1];
            for (int j = 0; j < 16; ++j) h[j] = b0 * pos_w[j] + b1 * pos_w[16 + j] + pos_b[j];
            ln_relu16(h, ln1_g, ln1_b);
            for (int j = 0; j < 16; ++j) {
                float s = fc1_b[j];
                for (int k = 0; k < 16; ++k) s += h[k] * fc1_w[k * 16 + j];
                h2[j] = s;
            }
            ln_relu16(h2, ln2_g, ln2_b);
            for (int j = 0; j < 16; ++j) {
                float s = fc2_b[j];
                for (int k = 0; k < 16; ++k) s += h2[k] * fc2_w[k * 16 + j];
                h[j] = s;
            }
            ln_relu16(h, ln3_g, ln3_b);
            for (int j = 0; j < 8; ++j) {
                float s = fc3_b[j];
                for (int k = 0; k < 16; ++k) s += h[k] * fc3_w[k * 8 + j];
                pos_s[tid][j] = s;
            }
        }
        __syncthreads();
        for (int e = tid; e < 8 * 64 * 64; e += 256) {
            int hh = e >> 12, rem = e & 4095;
            int row = rem >> 6, c = rem & 63;
            int tj = c >> 4, mm = c & 15;
            rbp[hh * 4096 + row * 64 + mm * 4 + tj] = pos_s[rel_idx[row * 64 + c]][hh];
        }
    }
}

// ---------------------------------------------------------------------------
// fused, per-head waves. LDS 64KB -> 2 blocks/CU needs total regs <= 128.
// __launch_bounds__(512,4): 2nd arg = MIN WAVES PER SIMD (guide §1) -> reg
// budget 512/4 = 128 TOTAL (arch VGPR + AGPR; AGPRs are invisible in
// rocprof's VGPR_Count but count against the unified file -> rounds 3-5 sat
// at 184 total = 2 waves/SIMD). Diet: S-recompute (no ph[32]), vT spilled to
// per-wave LDS slot (no long-lived vh), c2-sequential proj.
// LDS: [0,32K)  xs (x fp16) -> per-wave vT slots after B1 -> attn_out after B1.5
//      [32K,64K) 8 x 4KB per-wave arenas (qk transpose tiles / P chunks)
// Barriers: B0 xs ready | B1 xs reads done | B1.5 PV done | B2 attn ready.
// ---------------------------------------------------------------------------
__global__ __launch_bounds__(512, 4) void fused_kernel(
    const float* __restrict__ x,
    const half_t* __restrict__ wqkvT,
    const float* __restrict__ qkv_b,
    const half_t* __restrict__ wprojT,
    const float* __restrict__ proj_b,
    const float* __restrict__ rbp,
    float* __restrict__ out)
{
    __shared__ __align__(16) char smem[65536];
    char* xs  = smem;             // 32KB tri-purpose region
    char* atn = smem;             // alias (after B1.5)
    char* arenas = smem + 32768;

    const int b   = blockIdx.x;
    const int tid = threadIdx.x;
    const int w    = tid >> 6;
    const int lane = tid & 63;
    const int m = lane & 15;
    const int g = lane >> 4;
    char* wA  = arenas + w * 4096;   // transpose tiles / P chunks
    char* vts = xs + w * 4096;       // own vT slot (valid after B1)

    // ---- phase 0: x -> xs fp16 ----
    const float* xg = x + (size_t)b * 16384;
    #pragma unroll
    for (int i = 0; i < 8; ++i) {
        int u = tid + i * 512;
        int row = u >> 6, c4 = u & 63;
        float4v xv = *(const float4v*)(xg + u * 4);
        half4 hv;
        hv[0] = (half_t)xv[0]; hv[1] = (half_t)xv[1];
        hv[2] = (half_t)xv[2]; hv[3] = (half_t)xv[3];
        *(half4*)(xs + swzA(row, c4 * 8)) = hv;
    }
    __syncthreads();   // B0

    // ---- phase 1: q,k fragments for own head (role-swapped), arena transpose ----
    half8 aq[4], bk[4];
    #pragma unroll
    for (int pt = 0; pt < 2; ++pt) {          // 0: q, 1: k
        const int wrow0 = pt * 256 + w * 32;
        #pragma unroll
        for (int c2 = 0; c2 < 2; ++c2) {
            float4v a4[4];
            #pragma unroll
            for (int ti = 0; ti < 4; ++ti) a4[ti] = {0.f, 0.f, 0.f, 0.f};
            #pragma unroll
            for (int kk = 0; kk < 8; ++kk) {
                half8 wf = *(const half8*)(wqkvT + (size_t)(wrow0 + c2 * 16 + m) * 256 + kk * 32 + g * 8);
                #pragma unroll
                for (int ti = 0; ti < 4; ++ti) {
                    half8 af = *(const half8*)(xs + swzA(ti * 16 + m, kk * 64 + g * 16));
                    a4[ti] = mfma16(wf, af, a4[ti]);   // A=W rows d, B=x^T
                }
            }
            float4v b4 = *(const float4v*)(qkv_b + wrow0 + c2 * 16 + g * 4);
            #pragma unroll
            for (int ti = 0; ti < 4; ++ti) {
                half4 t;
                #pragma unroll
                for (int r = 0; r < 4; ++r) t[r] = (half_t)(a4[ti][r] + b4[r]);
                *(half4*)(wA + ti * 1024 + swzB(m, (c2 * 16 + g * 4) * 2)) = t;
            }
        }
        #pragma unroll
        for (int ti = 0; ti < 4; ++ti) {
            half8 fr = *(const half8*)(wA + ti * 1024 + swzB(m, g * 16));
            if (pt == 0) aq[ti] = fr; else bk[ti] = fr;
        }
        __builtin_amdgcn_sched_barrier(0);   // pt=0 reads before pt=1 writes
    }

    // ---- phase 2: S-sum pass -> rinv only (S recomputed in PV) ----
    float rinv[4][4];
    const float* rbh = rbp + w * 4096;
    #pragma unroll
    for (int ti = 0; ti < 4; ++ti) {
        float4v z = {0.f, 0.f, 0.f, 0.f};
        float4v s0 = mfma16(aq[ti], bk[0], z);
        float4v s1 = mfma16(aq[ti], bk[1], z);
        float4v s2 = mfma16(aq[ti], bk[2], z);
        float4v s3 = mfma16(aq[ti], bk[3], z);
        #pragma unroll
        for (int r = 0; r < 4; ++r) {
            float4v rb = *(const float4v*)(rbh + (ti * 16 + g * 4 + r) * 64 + m * 4);
            float e0 = __expf(s0[r] * QK_SCALE + rb[0]);
            float e1 = __expf(s1[r] * QK_SCALE + rb[1]);
            float e2 = __expf(s2[r] * QK_SCALE + rb[2]);
            float e3 = __expf(s3[r] * QK_SCALE + rb[3]);
            float s = e0 + e1 + e2 + e3;
            s += __shfl_xor(s, 1); s += __shfl_xor(s, 2);
            s += __shfl_xor(s, 4); s += __shfl_xor(s, 8);
            rinv[ti][r] = 1.0f / s;
        }
    }

    // ---- phase 3: v for own head (normal-role), short-lived vh regs ----
    half4 vh[2][4];                 // (d = c2*16+m, n = ti*16+g*4+r)
    #pragma unroll
    for (int c2 = 0; c2 < 2; ++c2) {
        const int wrow0 = 512 + w * 32;
        float4v a4[4];
        #pragma unroll
        for (int ti = 0; ti < 4; ++ti) a4[ti] = {0.f, 0.f, 0.f, 0.f};
        #pragma unroll
        for (int kk = 0; kk < 8; ++kk) {
            half8 wf = *(const half8*)(wqkvT + (size_t)(wrow0 + c2 * 16 + m) * 256 + kk * 32 + g * 8);
            #pragma unroll
            for (int ti = 0; ti < 4; ++ti) {
                half8 af = *(const half8*)(xs + swzA(ti * 16 + m, kk * 64 + g * 16));
                a4[ti] = mfma16(af, wf, a4[ti]);   // A=x rows n, B=W cols d
            }
        }
        float vb = qkv_b[wrow0 + c2 * 16 + m];
        #pragma unroll
        for (int ti = 0; ti < 4; ++ti)
            #pragma unroll
            for (int r = 0; r < 4; ++r)
                vh[c2][ti][r] = (half_t)(a4[ti][r] + vb);
    }
    __syncthreads();   // B1: xs reads done -> xs region becomes vT slots

    // vT [32 d][64 n] into own slot (wave-private; vh dies here)
    #pragma unroll
    for (int c2 = 0; c2 < 2; ++c2)
        #pragma unroll
        for (int ti = 0; ti < 4; ++ti)
            *(half4*)(vts + swzC(c2 * 16 + m, ti * 32 + g * 8)) = vh[c2][ti];

    // ---- phase 4: PV with S-recompute, nc chunks of 32 k-cols ----
    float4v oacc[2][4];
    #pragma unroll
    for (int tjd = 0; tjd < 2; ++tjd)
        #pragma unroll
        for (int ti = 0; ti < 4; ++ti) oacc[tjd][ti] = {0.f, 0.f, 0.f, 0.f};
    #pragma unroll
    for (int nc = 0; nc < 2; ++nc) {
        #pragma unroll
        for (int ti = 0; ti < 4; ++ti) {
            float4v z = {0.f, 0.f, 0.f, 0.f};
            float4v sa = mfma16(aq[ti], bk[2 * nc], z);
            float4v sb = mfma16(aq[ti], bk[2 * nc + 1], z);
            #pragma unroll
            for (int r = 0; r < 4; ++r) {
                int row = ti * 16 + g * 4 + r;
                float4v rb = *(const float4v*)(rbh + row * 64 + m * 4);
                float pa_ = __expf(sa[r] * QK_SCALE + rb[2 * nc])     * rinv[ti][r];
                float pb_ = __expf(sb[r] * QK_SCALE + rb[2 * nc + 1]) * rinv[ti][r];
                *(half_t*)(wA + swzB(row, m * 2))      = (half_t)pa_;
                *(half_t*)(wA + swzB(row, 32 + m * 2)) = (half_t)pb_;
            }
        }
        #pragma unroll
        for (int tjd = 0; tjd < 2; ++tjd) {
            half8 bv = *(const half8*)(vts + swzC(tjd * 16 + m, nc * 64 + g * 16));
            #pragma unroll
            for (int ti = 0; ti < 4; ++ti) {
                half8 pa = *(const half8*)(wA + swzB(ti * 16 + m, g * 16));
                oacc[tjd][ti] = mfma16(pa, bv, oacc[tjd][ti]);
            }
        }
        __builtin_amdgcn_sched_barrier(0);   // order nc iterations (arena reuse)
    }
    __syncthreads();   // B1.5: all PV reads of vT done -> region becomes attn_out

    // attn write (already normalized): own head's 32 cols
    #pragma unroll
    for (int tjd = 0; tjd < 2; ++tjd)
        #pragma unroll
        for (int ti = 0; ti < 4; ++ti)
            #pragma unroll
            for (int r = 0; r < 4; ++r)
                *(half_t*)(atn + swzA(ti * 16 + g * 4 + r, (w * 32 + tjd * 16 + m) * 2)) =
                    (half_t)oacc[tjd][ti][r];
    __syncthreads();   // B2: attn_out ready

    // ---- phase 5: proj GEMM + bias -> out (c2-sequential, 16-reg acc) ----
    float* og = out + (size_t)b * 16384;
    const int oc0 = w * 32;
    #pragma unroll
    for (int c2 = 0; c2 < 2; ++c2) {
        float4v p4[4];
        #pragma unroll
        for (int ti = 0; ti < 4; ++ti) p4[ti] = {0.f, 0.f, 0.f, 0.f};
        #pragma unroll
        for (int kk = 0; kk < 8; ++kk) {
            half8 wf = *(const half8*)(wprojT + (size_t)(oc0 + c2 * 16 + m) * 256 + kk * 32 + g * 8);
            #pragma unroll
            for (int ti = 0; ti < 4; ++ti) {
                half8 af = *(const half8*)(atn + swzA(ti * 16 + m, kk * 64 + g * 16));
                p4[ti] = mfma16(af, wf, p4[ti]);
            }
        }
        float pb = proj_b[oc0 + c2 * 16 + m];
        #pragma unroll
        for (int ti = 0; ti < 4; ++ti)
            #pragma unroll
            for (int r = 0; r < 4; ++r)
                og[(ti * 16 + g * 4 + r) * 256 + oc0 + c2 * 16 + m] = p4[ti][r] + pb;
    }
}

extern "C" void kernel_launch(void* const* d_in, const int* in_sizes, int n_in,
                              void* d_out, int out_size, void* d_ws, size_t ws_size,
                              hipStream_t stream) {
    const float* x          = (const float*)d_in[0];
    const float* qkv_w      = (const float*)d_in[1];
    const float* qkv_b      = (const float*)d_in[2];
    const float* proj_w     = (const float*)d_in[3];
    const float* proj_b     = (const float*)d_in[4];
    const float* pos_proj_w = (const float*)d_in[5];
    const float* pos_proj_b = (const float*)d_in[6];
    const float* ln1_g = (const float*)d_in[7];
    const float* ln1_b = (const float*)d_in[8];
    const float* fc1_w = (const float*)d_in[9];
    const float* fc1_b = (const float*)d_in[10];
    const float* ln2_g = (const float*)d_in[11];
    const float* ln2_b = (const float*)d_in[12];
    const float* fc2_w = (const float*)d_in[13];
    const float* fc2_b = (const float*)d_in[14];
    const float* ln3_g = (const float*)d_in[15];
    const float* ln3_b = (const float*)d_in[16];
    const float* fc3_w = (const float*)d_in[17];
    const float* fc3_b = (const float*)d_in[18];
    const float* biases = (const float*)d_in[19];
    const int*  rel_idx = (const int*)d_in[20];

    half_t* wqkvT  = (half_t*)d_ws;
    half_t* wprojT = (half_t*)((char*)d_ws + 393216);
    float*  rbp    = (float*)((char*)d_ws + 524288);

    const int B = in_sizes[0] / (64 * 256);

    prep_kernel<<<65, 256, 0, stream>>>(qkv_w, proj_w, biases, pos_proj_w, pos_proj_b,
                                        ln1_g, ln1_b, fc1_w, fc1_b,
                                        ln2_g, ln2_b, fc2_w, fc2_b,
                                        ln3_g, ln3_b, fc3_w, fc3_b,
                                        rel_idx, wqkvT, wprojT, rbp);
    fused_kernel<<<B, 512, 0, stream>>>(x, wqkvT, qkv_b, wprojT, proj_b, rbp,
                                        (float*)d_out);
}

// Round 7
// 345.278 us; speedup vs baseline: 1.6835x; 1.6835x over previous
//
#include <hip/hip_runtime.h>

typedef _Float16 half_t;
typedef __attribute__((ext_vector_type(8))) _Float16 half8;
typedef __attribute__((ext_vector_type(4))) _Float16 half4;
typedef __attribute__((ext_vector_type(4))) float float4v;

#define LN_EPS 1e-5f
#define QK_SCALE 0.17677669529663687f   // 32^-0.5

static __device__ __forceinline__ float4v mfma16(half8 a, half8 b, float4v c) {
    return __builtin_amdgcn_mfma_f32_16x16x32_f16(a, b, c, 0, 0, 0);
}

// 512B rows, XOR key (row>>1)&7
static __device__ __forceinline__ int swzA(int row, int colByte) {
    return row * 512 + ((((colByte >> 4) ^ ((row >> 1) & 7)) << 4) | (colByte & 15));
}
// 64B rows, XOR key (row>>1)&3
static __device__ __forceinline__ int swzB(int row, int colByte) {
    return row * 64 + ((((colByte >> 4) ^ ((row >> 1) & 3)) << 4) | (colByte & 15));
}

static __device__ void ln_relu16(float* h, const float* __restrict__ g, const float* __restrict__ b) {
    float m = 0.f;
    for (int j = 0; j < 16; ++j) m += h[j];
    m *= (1.0f / 16.0f);
    float v = 0.f;
    for (int j = 0; j < 16; ++j) { float d = h[j] - m; v += d * d; }
    v *= (1.0f / 16.0f);
    float rs = rsqrtf(v + LN_EPS);
    for (int j = 0; j < 16; ++j) {
        float t = (h[j] - m) * rs * g[j] + b[j];
        h[j] = t > 0.f ? t : 0.f;
    }
}

// ---------------------------------------------------------------------------
// prep: weight transpose+fp16, pos-bias MLP, rel-bias table rbp[h][row][m][tj]
// ---------------------------------------------------------------------------
__global__ void prep_kernel(
    const float* __restrict__ qkv_w,   // [256,768]
    const float* __restrict__ proj_w,  // [256,256]
    const float* __restrict__ biases,  // [225,2]
    const float* __restrict__ pos_w, const float* __restrict__ pos_b,
    const float* __restrict__ ln1_g, const float* __restrict__ ln1_b,
    const float* __restrict__ fc1_w, const float* __restrict__ fc1_b,
    const float* __restrict__ ln2_g, const float* __restrict__ ln2_b,
    const float* __restrict__ fc2_w, const float* __restrict__ fc2_b,
    const float* __restrict__ ln3_g, const float* __restrict__ ln3_b,
    const float* __restrict__ fc3_w, const float* __restrict__ fc3_b,
    const int* __restrict__ rel_idx,   // [64,64]
    half_t* __restrict__ wqkvT,        // [768,256]
    half_t* __restrict__ wprojT,       // [256,256]
    float* __restrict__ rbp)           // [8][64][16][4]
{
    __shared__ float tile[64][65];
    __shared__ float pos_s[225][8];
    const int t = blockIdx.x;
    const int tid = threadIdx.x;

    if (t < 64) {
        const float* src; half_t* dst; int ncols, rg, cg;
        if (t < 48) { src = qkv_w;  dst = wqkvT;  ncols = 768; rg = t / 12;      cg = t % 12; }
        else        { src = proj_w; dst = wprojT; ncols = 256; rg = (t-48) >> 2; cg = (t-48) & 3; }
        const int r0 = tid >> 6, c = tid & 63;
        for (int i = 0; i < 16; ++i) {
            int r = i * 4 + r0;
            tile[r][c] = src[(rg * 64 + r) * ncols + cg * 64 + c];
        }
        __syncthreads();
        for (int i = 0; i < 16; ++i) {
            int r = i * 4 + r0;
            dst[(cg * 64 + r) * 256 + rg * 64 + c] = (half_t)tile[c][r];
        }
    } else {
        if (tid < 225) {
            float h[16], h2[16];
            float b0 = biases[tid * 2], b1 = biases[tid * 2 + 1];
            for (int j = 0; j < 16; ++j) h[j] = b0 * pos_w[j] + b1 * pos_w[16 + j] + pos_b[j];
            ln_relu16(h, ln1_g, ln1_b);
            for (int j = 0; j < 16; ++j) {
                float s = fc1_b[j];
                for (int k = 0; k < 16; ++k) s += h[k] * fc1_w[k * 16 + j];
                h2[j] = s;
            }
            ln_relu16(h2, ln2_g, ln2_b);
            for (int j = 0; j < 16; ++j) {
                float s = fc2_b[j];
                for (int k = 0; k < 16; ++k) s += h2[k] * fc2_w[k * 16 + j];
                h[j] = s;
            }
            ln_relu16(h, ln3_g, ln3_b);
            for (int j = 0; j < 8; ++j) {
                float s = fc3_b[j];
                for (int k = 0; k < 16; ++k) s += h[k] * fc3_w[k * 8 + j];
                pos_s[tid][j] = s;
            }
        }
        __syncthreads();
        for (int e = tid; e < 8 * 64 * 64; e += 256) {
            int hh = e >> 12, rem = e & 4095;
            int row = rem >> 6, c = rem & 63;
            int tj = c >> 4, mm = c & 15;
            rbp[hh * 4096 + row * 64 + mm * 4 + tj] = pos_s[rel_idx[row * 64 + c]][hh];
        }
    }
}

// ---------------------------------------------------------------------------
// fused: 256-thread block (4 waves) per window; wave w owns heads {w, w+4}
// sequentially. Occupancy granularity is the whole point (round-6 lesson):
// 512-thread blocks can only be 8 or 16 waves/CU and 16 needs <=128 total
// regs (incl. AGPRs -> spills). 4-wave blocks at <=170 total regs give
// 3 blocks/CU = 12 waves, three INDEPENDENT windows covering each other's
// barrier stalls. __launch_bounds__(256,3): 2nd arg = min waves/EU -> total
// reg budget 512/3 = 170 (arch VGPR + AGPR).
// LDS 52KB/block (3x52=156 <= 160):
//   [0,32K)    xs[64][512B] fp16 x  -> attn_out overlay after B1
//   [32K,52K)  4 x 5KB wave arenas: wA 4KB (qk-transpose tiles / P chunk),
//              wB 1KB (vT quarter staging, time-multiplexed per tjd)
// Barriers: B0 xs ready | B1 all xs reads done | B2 attn ready. Everything
// between B0 and B1 is wave-private (in-order DS + sched_barrier fences).
// ---------------------------------------------------------------------------
__global__ __launch_bounds__(256, 3) void fused_kernel(
    const float* __restrict__ x,
    const half_t* __restrict__ wqkvT,
    const float* __restrict__ qkv_b,
    const half_t* __restrict__ wprojT,
    const float* __restrict__ proj_b,
    const float* __restrict__ rbp,
    float* __restrict__ out)
{
    __shared__ __align__(16) char smem[53248];
    char* xs  = smem;             // 32KB, becomes attn_out after B1
    char* atn = smem;             // alias

    const int b   = blockIdx.x;
    const int tid = threadIdx.x;
    const int w    = tid >> 6;    // wave 0..3
    const int lane = tid & 63;
    const int m = lane & 15;
    const int g = lane >> 4;
    char* wA = smem + 32768 + w * 5120;   // 4KB
    char* wB = wA + 4096;                 // 1KB

    // ---- phase 0: x -> xs fp16 ----
    const float* xg = x + (size_t)b * 16384;
    #pragma unroll
    for (int i = 0; i < 16; ++i) {
        int u = tid + i * 256;
        int row = u >> 6, c4 = u & 63;
        float4v xv = *(const float4v*)(xg + u * 4);
        half4 hv;
        hv[0] = (half_t)xv[0]; hv[1] = (half_t)xv[1];
        hv[2] = (half_t)xv[2]; hv[3] = (half_t)xv[3];
        *(half4*)(xs + swzA(row, c4 * 8)) = hv;
    }
    __syncthreads();   // B0

    half4 oh[2][2][4];   // attn result fp16, [hh][tjd][ti] (all indices static)

    #pragma unroll
    for (int hh = 0; hh < 2; ++hh) {
        const int h = w + hh * 4;
        const float* rbh = rbp + h * 4096;

        // ---- phase 1: q,k (role-swapped MFMA), wA transpose roundtrip ----
        half8 aq[4], bk[4];
        #pragma unroll
        for (int pt = 0; pt < 2; ++pt) {      // 0: q, 1: k
            const int wrow0 = pt * 256 + h * 32;
            #pragma unroll
            for (int c2 = 0; c2 < 2; ++c2) {
                float4v a4[4];
                #pragma unroll
                for (int ti = 0; ti < 4; ++ti) a4[ti] = {0.f, 0.f, 0.f, 0.f};
                #pragma unroll
                for (int kk = 0; kk < 8; ++kk) {
                    half8 wf = *(const half8*)(wqkvT + (size_t)(wrow0 + c2 * 16 + m) * 256 + kk * 32 + g * 8);
                    #pragma unroll
                    for (int ti = 0; ti < 4; ++ti) {
                        half8 af = *(const half8*)(xs + swzA(ti * 16 + m, kk * 64 + g * 16));
                        a4[ti] = mfma16(wf, af, a4[ti]);   // A=W rows d, B=x^T
                    }
                }
                float4v b4 = *(const float4v*)(qkv_b + wrow0 + c2 * 16 + g * 4);
                #pragma unroll
                for (int ti = 0; ti < 4; ++ti) {
                    half4 t;
                    #pragma unroll
                    for (int r = 0; r < 4; ++r) t[r] = (half_t)(a4[ti][r] + b4[r]);
                    *(half4*)(wA + ti * 1024 + swzB(m, (c2 * 16 + g * 4) * 2)) = t;
                }
            }
            #pragma unroll
            for (int ti = 0; ti < 4; ++ti) {
                half8 fr = *(const half8*)(wA + ti * 1024 + swzB(m, g * 16));
                if (pt == 0) aq[ti] = fr; else bk[ti] = fr;
            }
            __builtin_amdgcn_sched_barrier(0);   // reads before next pt's writes
        }

        // ---- phase 2: S = q k^T + bias, softmax; pre-normalized P in regs ----
        half4 ph[4][4];               // ph[ti][tj][r] = exp(S)/sum  (no max-sub)
        #pragma unroll
        for (int ti = 0; ti < 4; ++ti) {
            float4v z = {0.f, 0.f, 0.f, 0.f};
            float4v s0 = mfma16(aq[ti], bk[0], z);
            float4v s1 = mfma16(aq[ti], bk[1], z);
            float4v s2 = mfma16(aq[ti], bk[2], z);
            float4v s3 = mfma16(aq[ti], bk[3], z);
            #pragma unroll
            for (int r = 0; r < 4; ++r) {
                float4v rb = *(const float4v*)(rbh + (ti * 16 + g * 4 + r) * 64 + m * 4);
                float e0 = __expf(s0[r] * QK_SCALE + rb[0]);
                float e1 = __expf(s1[r] * QK_SCALE + rb[1]);
                float e2 = __expf(s2[r] * QK_SCALE + rb[2]);
                float e3 = __expf(s3[r] * QK_SCALE + rb[3]);
                float s = e0 + e1 + e2 + e3;
                s += __shfl_xor(s, 1); s += __shfl_xor(s, 2);
                s += __shfl_xor(s, 4); s += __shfl_xor(s, 8);
                float is = 1.0f / s;
                ph[ti][0][r] = (half_t)(e0 * is);
                ph[ti][1][r] = (half_t)(e1 * is);
                ph[ti][2][r] = (half_t)(e2 * is);
                ph[ti][3][r] = (half_t)(e3 * is);
            }
        }

        // ---- phase 3: v (normal-role MFMA), packed in regs ----
        half4 vh[2][4];               // (d = c2*16+m, n = ti*16+g*4+r)
        #pragma unroll
        for (int c2 = 0; c2 < 2; ++c2) {
            const int wrow0 = 512 + h * 32;
            float4v a4[4];
            #pragma unroll
            for (int ti = 0; ti < 4; ++ti) a4[ti] = {0.f, 0.f, 0.f, 0.f};
            #pragma unroll
            for (int kk = 0; kk < 8; ++kk) {
                half8 wf = *(const half8*)(wqkvT + (size_t)(wrow0 + c2 * 16 + m) * 256 + kk * 32 + g * 8);
                #pragma unroll
                for (int ti = 0; ti < 4; ++ti) {
                    half8 af = *(const half8*)(xs + swzA(ti * 16 + m, kk * 64 + g * 16));
                    a4[ti] = mfma16(af, wf, a4[ti]);   // A=x rows n, B=W cols d
                }
            }
            float vb = qkv_b[wrow0 + c2 * 16 + m];
            #pragma unroll
            for (int ti = 0; ti < 4; ++ti)
                #pragma unroll
                for (int r = 0; r < 4; ++r)
                    vh[c2][ti][r] = (half_t)(a4[ti][r] + vb);
        }

        // ---- phase 4: PV, nc chunks of 32 k-cols; P written once per nc,
        //      vT quarters time-multiplexed through 1KB wB ----
        float4v oacc[2][4];
        #pragma unroll
        for (int tjd = 0; tjd < 2; ++tjd)
            #pragma unroll
            for (int ti = 0; ti < 4; ++ti) oacc[tjd][ti] = {0.f, 0.f, 0.f, 0.f};
        #pragma unroll
        for (int nc = 0; nc < 2; ++nc) {
            // P chunk [64 n_q][32 n_k] into wA
            #pragma unroll
            for (int ti = 0; ti < 4; ++ti)
                #pragma unroll
                for (int t2 = 0; t2 < 2; ++t2)
                    #pragma unroll
                    for (int r = 0; r < 4; ++r)
                        *(half_t*)(wA + swzB(ti * 16 + g * 4 + r, (t2 * 16 + m) * 2)) =
                            ph[ti][nc * 2 + t2][r];
            half8 pa[4];
            #pragma unroll
            for (int ti = 0; ti < 4; ++ti)
                pa[ti] = *(const half8*)(wA + swzB(ti * 16 + m, g * 16));
            __builtin_amdgcn_sched_barrier(0);
            #pragma unroll
            for (int tjd = 0; tjd < 2; ++tjd) {
                #pragma unroll
                for (int t2 = 0; t2 < 2; ++t2)
                    *(half4*)(wB + swzB(m, (t2 * 16 + g * 4) * 2)) = vh[tjd][nc * 2 + t2];
                half8 bv = *(const half8*)(wB + swzB(m, g * 16));
                #pragma unroll
                for (int ti = 0; ti < 4; ++ti)
                    oacc[tjd][ti] = mfma16(pa[ti], bv, oacc[tjd][ti]);
                __builtin_amdgcn_sched_barrier(0);   // bv read before next tjd write
            }
        }
        #pragma unroll
        for (int tjd = 0; tjd < 2; ++tjd)
            #pragma unroll
            for (int ti = 0; ti < 4; ++ti)
                #pragma unroll
                for (int r = 0; r < 4; ++r)
                    oh[hh][tjd][ti][r] = (half_t)oacc[tjd][ti][r];
        __builtin_amdgcn_sched_barrier(0);   // arena reads done before next head
    }
    __syncthreads();   // B1: all xs reads done -> xs region becomes attn_out

    // attn write (already normalized): head h cols h*32 + tjd*16 + m
    #pragma unroll
    for (int hh = 0; hh < 2; ++hh)
        #pragma unroll
        for (int tjd = 0; tjd < 2; ++tjd)
            #pragma unroll
            for (int ti = 0; ti < 4; ++ti)
                #pragma unroll
                for (int r = 0; r < 4; ++r)
                    *(half_t*)(atn + swzA(ti * 16 + g * 4 + r,
                                          ((w + hh * 4) * 32 + tjd * 16 + m) * 2)) =
                        oh[hh][tjd][ti][r];
    __syncthreads();   // B2: attn_out ready

    // ---- phase 5: proj GEMM + bias -> out; wave w owns cols w*64..w*64+63 ----
    float* og = out + (size_t)b * 16384;
    #pragma unroll
    for (int c4 = 0; c4 < 4; ++c4) {
        const int oc0 = w * 64 + c4 * 16;
        float4v p4[4];
        #pragma unroll
        for (int ti = 0; ti < 4; ++ti) p4[ti] = {0.f, 0.f, 0.f, 0.f};
        #pragma unroll
        for (int kk = 0; kk < 8; ++kk) {
            half8 wf = *(const half8*)(wprojT + (size_t)(oc0 + m) * 256 + kk * 32 + g * 8);
            #pragma unroll
            for (int ti = 0; ti < 4; ++ti) {
                half8 af = *(const half8*)(atn + swzA(ti * 16 + m, kk * 64 + g * 16));
                p4[ti] = mfma16(af, wf, p4[ti]);
            }
        }
        float pb = proj_b[oc0 + m];
        #pragma unroll
        for (int ti = 0; ti < 4; ++ti)
            #pragma unroll
            for (int r = 0; r < 4; ++r)
                og[(ti * 16 + g * 4 + r) * 256 + oc0 + m] = p4[ti][r] + pb;
    }
}

extern "C" void kernel_launch(void* const* d_in, const int* in_sizes, int n_in,
                              void* d_out, int out_size, void* d_ws, size_t ws_size,
                              hipStream_t stream) {
    const float* x          = (const float*)d_in[0];
    const float* qkv_w      = (const float*)d_in[1];
    const float* qkv_b      = (const float*)d_in[2];
    const float* proj_w     = (const float*)d_in[3];
    const float* proj_b     = (const float*)d_in[4];
    const float* pos_proj_w = (const float*)d_in[5];
    const float* pos_proj_b = (const float*)d_in[6];
    const float* ln1_g = (const float*)d_in[7];
    const float* ln1_b = (const float*)d_in[8];
    const float* fc1_w = (const float*)d_in[9];
    const float* fc1_b = (const float*)d_in[10];
    const float* ln2_g = (const float*)d_in[11];
    const float* ln2_b = (const float*)d_in[12];
    const float* fc2_w = (const float*)d_in[13];
    const float* fc2_b = (const float*)d_in[14];
    const float* ln3_g = (const float*)d_in[15];
    const float* ln3_b = (const float*)d_in[16];
    const float* fc3_w = (const float*)d_in[17];
    const float* fc3_b = (const float*)d_in[18];
    const float* biases = (const float*)d_in[19];
    const int*  rel_idx = (const int*)d_in[20];

    half_t* wqkvT  = (half_t*)d_ws;
    half_t* wprojT = (half_t*)((char*)d_ws + 393216);
    float*  rbp    = (float*)((char*)d_ws + 524288);

    const int B = in_sizes[0] / (64 * 256);

    prep_kernel<<<65, 256, 0, stream>>>(qkv_w, proj_w, biases, pos_proj_w, pos_proj_b,
                                        ln1_g, ln1_b, fc1_w, fc1_b,
                                        ln2_g, ln2_b, fc2_w, fc2_b,
                                        ln3_g, ln3_b, fc3_w, fc3_b,
                                        rel_idx, wqkvT, wprojT, rbp);
    fused_kernel<<<B, 256, 0, stream>>>(x, wqkvT, qkv_b, wprojT, proj_b, rbp,
                                        (float*)d_out);
}

// Round 8
// 264.248 us; speedup vs baseline: 2.1997x; 1.3066x over previous
//
#include <hip/hip_runtime.h>

typedef _Float16 half_t;
typedef __attribute__((ext_vector_type(8))) _Float16 half8;
typedef __attribute__((ext_vector_type(4))) _Float16 half4;
typedef __attribute__((ext_vector_type(4))) float float4v;

#define LN_EPS 1e-5f
#define QK_SCALE 0.17677669529663687f   // 32^-0.5

static __device__ __forceinline__ float4v mfma16(half8 a, half8 b, float4v c) {
    return __builtin_amdgcn_mfma_f32_16x16x32_f16(a, b, c, 0, 0, 0);
}

// 512B rows, XOR key (row>>1)&7
static __device__ __forceinline__ int swzA(int row, int colByte) {
    return row * 512 + ((((colByte >> 4) ^ ((row >> 1) & 7)) << 4) | (colByte & 15));
}
// 64B rows, XOR key (row>>1)&3
static __device__ __forceinline__ int swzB(int row, int colByte) {
    return row * 64 + ((((colByte >> 4) ^ ((row >> 1) & 3)) << 4) | (colByte & 15));
}
// 128B rows, XOR key row&7 (vT slots: 32 rows x 128B)
static __device__ __forceinline__ int swzC(int row, int colByte) {
    return row * 128 + ((((colByte >> 4) ^ (row & 7)) << 4) | (colByte & 15));
}

static __device__ void ln_relu16(float* h, const float* __restrict__ g, const float* __restrict__ b) {
    float m = 0.f;
    for (int j = 0; j < 16; ++j) m += h[j];
    m *= (1.0f / 16.0f);
    float v = 0.f;
    for (int j = 0; j < 16; ++j) { float d = h[j] - m; v += d * d; }
    v *= (1.0f / 16.0f);
    float rs = rsqrtf(v + LN_EPS);
    for (int j = 0; j < 16; ++j) {
        float t = (h[j] - m) * rs * g[j] + b[j];
        h[j] = t > 0.f ? t : 0.f;
    }
}

// ---------------------------------------------------------------------------
// prep: weight transpose+fp16, pos-bias MLP, rel-bias table rbp[h][row][m][tj]
// ---------------------------------------------------------------------------
__global__ void prep_kernel(
    const float* __restrict__ qkv_w,   // [256,768]
    const float* __restrict__ proj_w,  // [256,256]
    const float* __restrict__ biases,  // [225,2]
    const float* __restrict__ pos_w, const float* __restrict__ pos_b,
    const float* __restrict__ ln1_g, const float* __restrict__ ln1_b,
    const float* __restrict__ fc1_w, const float* __restrict__ fc1_b,
    const float* __restrict__ ln2_g, const float* __restrict__ ln2_b,
    const float* __restrict__ fc2_w, const float* __restrict__ fc2_b,
    const float* __restrict__ ln3_g, const float* __restrict__ ln3_b,
    const float* __restrict__ fc3_w, const float* __restrict__ fc3_b,
    const int* __restrict__ rel_idx,   // [64,64]
    half_t* __restrict__ wqkvT,        // [768,256]
    half_t* __restrict__ wprojT,       // [256,256]
    float* __restrict__ rbp)           // [8][64][16][4]
{
    __shared__ float tile[64][65];
    __shared__ float pos_s[225][8];
    const int t = blockIdx.x;
    const int tid = threadIdx.x;

    if (t < 64) {
        const float* src; half_t* dst; int ncols, rg, cg;
        if (t < 48) { src = qkv_w;  dst = wqkvT;  ncols = 768; rg = t / 12;      cg = t % 12; }
        else        { src = proj_w; dst = wprojT; ncols = 256; rg = (t-48) >> 2; cg = (t-48) & 3; }
        const int r0 = tid >> 6, c = tid & 63;
        for (int i = 0; i < 16; ++i) {
            int r = i * 4 + r0;
            tile[r][c] = src[(rg * 64 + r) * ncols + cg * 64 + c];
        }
        __syncthreads();
        for (int i = 0; i < 16; ++i) {
            int r = i * 4 + r0;
            dst[(cg * 64 + r) * 256 + rg * 64 + c] = (half_t)tile[c][r];
        }
    } else {
        if (tid < 225) {
            float h[16], h2[16];
            float b0 = biases[tid * 2], b1 = biases[tid * 2 + 1];
            for (int j = 0; j < 16; ++j) h[j] = b0 * pos_w[j] + b1 * pos_w[16 + j] + pos_b[j];
            ln_relu16(h, ln1_g, ln1_b);
            for (int j = 0; j < 16; ++j) {
                float s = fc1_b[j];
                for (int k = 0; k < 16; ++k) s += h[k] * fc1_w[k * 16 + j];
                h2[j] = s;
            }
            ln_relu16(h2, ln2_g, ln2_b);
            for (int j = 0; j < 16; ++j) {
                float s = fc2_b[j];
                for (int k = 0; k < 16; ++k) s += h2[k] * fc2_w[k * 16 + j];
                h[j] = s;
            }
            ln_relu16(h, ln3_g, ln3_b);
            for (int j = 0; j < 8; ++j) {
                float s = fc3_b[j];
                for (int k = 0; k < 16; ++k) s += h[k] * fc3_w[k * 8 + j];
                pos_s[tid][j] = s;
            }
        }
        __syncthreads();
        for (int e = tid; e < 8 * 64 * 64; e += 256) {
            int hh = e >> 12, rem = e & 4095;
            int row = rem >> 6, c = rem & 63;
            int tj = c >> 4, mm = c & 15;
            rbp[hh * 4096 + row * 64 + mm * 4 + tj] = pos_s[rel_idx[row * 64 + c]][hh];
        }
    }
}

// ---------------------------------------------------------------------------
// fused, per-head waves. R5 shell (proven): 512 thr, 64KB LDS, (512,2).
// Occupancy locked at 8 waves/CU (16 waves needs <=128 total regs incl.
// AGPR -> spills, proven R2/R6/R7). This round: shorten the per-wave serial
// chain instead -- kk-outer loops (af LDS reads reused x4/x2; 16 indep MFMAs
// per step), ph kept in regs (no S-recompute, halves exp count), fewer
// sched_barrier regions.
// LDS: [0,32K)  xs (x fp16) -> per-wave vT slots after B1 -> attn_out after B1.5
//      [32K,64K) 8 x 4KB per-wave arenas (qk transpose tiles / P chunks)
// Barriers: B0 xs ready | B1 xs reads done | B1.5 PV done | B2 attn ready.
// ---------------------------------------------------------------------------
__global__ __launch_bounds__(512, 2) void fused_kernel(
    const float* __restrict__ x,
    const half_t* __restrict__ wqkvT,
    const float* __restrict__ qkv_b,
    const half_t* __restrict__ wprojT,
    const float* __restrict__ proj_b,
    const float* __restrict__ rbp,
    float* __restrict__ out)
{
    __shared__ __align__(16) char smem[65536];
    char* xs  = smem;             // 32KB tri-purpose region
    char* atn = smem;             // alias (after B1.5)
    char* arenas = smem + 32768;

    const int b   = blockIdx.x;
    const int tid = threadIdx.x;
    const int w    = tid >> 6;
    const int lane = tid & 63;
    const int m = lane & 15;
    const int g = lane >> 4;
    char* wA  = arenas + w * 4096;   // transpose tiles / P chunks
    char* vts = xs + w * 4096;       // own vT slot (valid after B1)

    // ---- phase 0: x -> xs fp16 ----
    const float* xg = x + (size_t)b * 16384;
    #pragma unroll
    for (int i = 0; i < 8; ++i) {
        int u = tid + i * 512;
        int row = u >> 6, c4 = u & 63;
        float4v xv = *(const float4v*)(xg + u * 4);
        half4 hv;
        hv[0] = (half_t)xv[0]; hv[1] = (half_t)xv[1];
        hv[2] = (half_t)xv[2]; hv[3] = (half_t)xv[3];
        *(half4*)(xs + swzA(row, c4 * 8)) = hv;
    }
    __syncthreads();   // B0

    // bias fragments for q,k (role-swapped C rows = d = c2*16+g*4+r)
    float4v qb[2][2];
    #pragma unroll
    for (int pt = 0; pt < 2; ++pt)
        #pragma unroll
        for (int c2 = 0; c2 < 2; ++c2)
            qb[pt][c2] = *(const float4v*)(qkv_b + pt * 256 + w * 32 + c2 * 16 + g * 4);

    // ---- phase 1: q,k joint, kk-outer (af reused x4; 16 indep MFMA/kk) ----
    half8 aq[4], bk[4];
    {
        float4v qa[2][4], ka[2][4];
        #pragma unroll
        for (int c2 = 0; c2 < 2; ++c2)
            #pragma unroll
            for (int ti = 0; ti < 4; ++ti) {
                qa[c2][ti] = {0.f, 0.f, 0.f, 0.f};
                ka[c2][ti] = {0.f, 0.f, 0.f, 0.f};
            }
        const half_t* wqb = wqkvT + (size_t)(w * 32 + m) * 256 + g * 8;
        #pragma unroll
        for (int kk = 0; kk < 8; ++kk) {
            half8 af[4];
            #pragma unroll
            for (int ti = 0; ti < 4; ++ti)
                af[ti] = *(const half8*)(xs + swzA(ti * 16 + m, kk * 64 + g * 16));
            half8 wq0 = *(const half8*)(wqb + kk * 32);
            half8 wq1 = *(const half8*)(wqb + 16 * 256 + kk * 32);
            half8 wk0 = *(const half8*)(wqb + 256 * 256 + kk * 32);
            half8 wk1 = *(const half8*)(wqb + 272 * 256 + kk * 32);
            #pragma unroll
            for (int ti = 0; ti < 4; ++ti) {
                qa[0][ti] = mfma16(wq0, af[ti], qa[0][ti]);   // A=W rows d, B=x^T
                qa[1][ti] = mfma16(wq1, af[ti], qa[1][ti]);
                ka[0][ti] = mfma16(wk0, af[ti], ka[0][ti]);
                ka[1][ti] = mfma16(wk1, af[ti], ka[1][ti]);
            }
        }
        // q tiles -> wA -> aq frags
        #pragma unroll
        for (int c2 = 0; c2 < 2; ++c2)
            #pragma unroll
            for (int ti = 0; ti < 4; ++ti) {
                half4 t;
                #pragma unroll
                for (int r = 0; r < 4; ++r) t[r] = (half_t)(qa[c2][ti][r] + qb[0][c2][r]);
                *(half4*)(wA + ti * 1024 + swzB(m, (c2 * 16 + g * 4) * 2)) = t;
            }
        #pragma unroll
        for (int ti = 0; ti < 4; ++ti)
            aq[ti] = *(const half8*)(wA + ti * 1024 + swzB(m, g * 16));
        __builtin_amdgcn_sched_barrier(0);   // aq reads before k-tile overwrite
        // k tiles -> wA -> bk frags
        #pragma unroll
        for (int c2 = 0; c2 < 2; ++c2)
            #pragma unroll
            for (int ti = 0; ti < 4; ++ti) {
                half4 t;
                #pragma unroll
                for (int r = 0; r < 4; ++r) t[r] = (half_t)(ka[c2][ti][r] + qb[1][c2][r]);
                *(half4*)(wA + ti * 1024 + swzB(m, (c2 * 16 + g * 4) * 2)) = t;
            }
        #pragma unroll
        for (int ti = 0; ti < 4; ++ti)
            bk[ti] = *(const half8*)(wA + ti * 1024 + swzB(m, g * 16));
        __builtin_amdgcn_sched_barrier(0);   // bk reads before later wA reuse
    }

    // ---- phase 2: S = q k^T + bias, softmax; pre-normalized P in regs ----
    half4 ph[4][4];               // ph[ti][tj][r] = exp(S)/sum  (no max-sub)
    const float* rbh = rbp + w * 4096;
    #pragma unroll
    for (int ti = 0; ti < 4; ++ti) {
        float4v z = {0.f, 0.f, 0.f, 0.f};
        float4v s0 = mfma16(aq[ti], bk[0], z);
        float4v s1 = mfma16(aq[ti], bk[1], z);
        float4v s2 = mfma16(aq[ti], bk[2], z);
        float4v s3 = mfma16(aq[ti], bk[3], z);
        #pragma unroll
        for (int r = 0; r < 4; ++r) {
            float4v rb = *(const float4v*)(rbh + (ti * 16 + g * 4 + r) * 64 + m * 4);
            float e0 = __expf(s0[r] * QK_SCALE + rb[0]);
            float e1 = __expf(s1[r] * QK_SCALE + rb[1]);
            float e2 = __expf(s2[r] * QK_SCALE + rb[2]);
            float e3 = __expf(s3[r] * QK_SCALE + rb[3]);
            float s = e0 + e1 + e2 + e3;
            s += __shfl_xor(s, 1); s += __shfl_xor(s, 2);
            s += __shfl_xor(s, 4); s += __shfl_xor(s, 8);
            float is = 1.0f / s;
            ph[ti][0][r] = (half_t)(e0 * is);
            ph[ti][1][r] = (half_t)(e1 * is);
            ph[ti][2][r] = (half_t)(e2 * is);
            ph[ti][3][r] = (half_t)(e3 * is);
        }
    }

    // ---- phase 3: v, kk-outer c2-paired (af reused x2) ----
    half4 vh[2][4];               // (d = c2*16+m, n = ti*16+g*4+r)
    {
        float4v va[2][4];
        #pragma unroll
        for (int c2 = 0; c2 < 2; ++c2)
            #pragma unroll
            for (int ti = 0; ti < 4; ++ti) va[c2][ti] = {0.f, 0.f, 0.f, 0.f};
        const half_t* wvb = wqkvT + (size_t)(512 + w * 32 + m) * 256 + g * 8;
        #pragma unroll
        for (int kk = 0; kk < 8; ++kk) {
            half8 wv0 = *(const half8*)(wvb + kk * 32);
            half8 wv1 = *(const half8*)(wvb + 16 * 256 + kk * 32);
            #pragma unroll
            for (int ti = 0; ti < 4; ++ti) {
                half8 af = *(const half8*)(xs + swzA(ti * 16 + m, kk * 64 + g * 16));
                va[0][ti] = mfma16(af, wv0, va[0][ti]);   // A=x rows n, B=W cols d
                va[1][ti] = mfma16(af, wv1, va[1][ti]);
            }
        }
        float vb0 = qkv_b[512 + w * 32 + m], vb1 = qkv_b[512 + w * 32 + 16 + m];
        #pragma unroll
        for (int c2 = 0; c2 < 2; ++c2)
            #pragma unroll
            for (int ti = 0; ti < 4; ++ti)
                #pragma unroll
                for (int r = 0; r < 4; ++r)
                    vh[c2][ti][r] = (half_t)(va[c2][ti][r] + (c2 ? vb1 : vb0));
    }
    __syncthreads();   // B1: xs reads done -> xs region becomes vT slots

    // vT [32 d][64 n] into own slot (wave-private; vh dies here)
    #pragma unroll
    for (int c2 = 0; c2 < 2; ++c2)
        #pragma unroll
        for (int ti = 0; ti < 4; ++ti)
            *(half4*)(vts + swzC(c2 * 16 + m, ti * 32 + g * 8)) = vh[c2][ti];

    // ---- phase 4: PV from ph, nc chunks of 32 k-cols ----
    float4v oacc[2][4];
    #pragma unroll
    for (int tjd = 0; tjd < 2; ++tjd)
        #pragma unroll
        for (int ti = 0; ti < 4; ++ti) oacc[tjd][ti] = {0.f, 0.f, 0.f, 0.f};
    #pragma unroll
    for (int nc = 0; nc < 2; ++nc) {
        // P chunk [64 n_q][32 n_k] into wA
        #pragma unroll
        for (int ti = 0; ti < 4; ++ti)
            #pragma unroll
            for (int t2 = 0; t2 < 2; ++t2)
                #pragma unroll
                for (int r = 0; r < 4; ++r)
                    *(half_t*)(wA + swzB(ti * 16 + g * 4 + r, (t2 * 16 + m) * 2)) =
                        ph[ti][nc * 2 + t2][r];
        half8 pa[4];
        #pragma unroll
        for (int ti = 0; ti < 4; ++ti)
            pa[ti] = *(const half8*)(wA + swzB(ti * 16 + m, g * 16));
        #pragma unroll
        for (int tjd = 0; tjd < 2; ++tjd) {
            half8 bv = *(const half8*)(vts + swzC(tjd * 16 + m, nc * 64 + g * 16));
            #pragma unroll
            for (int ti = 0; ti < 4; ++ti)
                oacc[tjd][ti] = mfma16(pa[ti], bv, oacc[tjd][ti]);
        }
        __builtin_amdgcn_sched_barrier(0);   // pa reads before next nc P overwrite
    }
    __syncthreads();   // B1.5: all PV reads of vT done -> region becomes attn_out

    // attn write (already normalized): own head's 32 cols
    #pragma unroll
    for (int tjd = 0; tjd < 2; ++tjd)
        #pragma unroll
        for (int ti = 0; ti < 4; ++ti)
            #pragma unroll
            for (int r = 0; r < 4; ++r)
                *(half_t*)(atn + swzA(ti * 16 + g * 4 + r, (w * 32 + tjd * 16 + m) * 2)) =
                    (half_t)oacc[tjd][ti][r];
    __syncthreads();   // B2: attn_out ready

    // ---- phase 5: proj GEMM + bias -> out, kk-outer c2-paired ----
    float* og = out + (size_t)b * 16384;
    const int oc0 = w * 32;
    float4v pacc[2][4];
    #pragma unroll
    for (int c2 = 0; c2 < 2; ++c2)
        #pragma unroll
        for (int ti = 0; ti < 4; ++ti) pacc[c2][ti] = {0.f, 0.f, 0.f, 0.f};
    const half_t* wpb = wprojT + (size_t)(oc0 + m) * 256 + g * 8;
    #pragma unroll
    for (int kk = 0; kk < 8; ++kk) {
        half8 wf0 = *(const half8*)(wpb + kk * 32);
        half8 wf1 = *(const half8*)(wpb + 16 * 256 + kk * 32);
        #pragma unroll
        for (int ti = 0; ti < 4; ++ti) {
            half8 af = *(const half8*)(atn + swzA(ti * 16 + m, kk * 64 + g * 16));
            pacc[0][ti] = mfma16(af, wf0, pacc[0][ti]);
            pacc[1][ti] = mfma16(af, wf1, pacc[1][ti]);
        }
    }
    float pb0 = proj_b[oc0 + m], pb1 = proj_b[oc0 + 16 + m];
    #pragma unroll
    for (int c2 = 0; c2 < 2; ++c2)
        #pragma unroll
        for (int ti = 0; ti < 4; ++ti)
            #pragma unroll
            for (int r = 0; r < 4; ++r)
                og[(ti * 16 + g * 4 + r) * 256 + oc0 + c2 * 16 + m] =
                    pacc[c2][ti][r] + (c2 ? pb1 : pb0);
}

extern "C" void kernel_launch(void* const* d_in, const int* in_sizes, int n_in,
                              void* d_out, int out_size, void* d_ws, size_t ws_size,
                              hipStream_t stream) {
    const float* x          = (const float*)d_in[0];
    const float* qkv_w      = (const float*)d_in[1];
    const float* qkv_b      = (const float*)d_in[2];
    const float* proj_w     = (const float*)d_in[3];
    const float* proj_b     = (const float*)d_in[4];
    const float* pos_proj_w = (const float*)d_in[5];
    const float* pos_proj_b = (const float*)d_in[6];
    const float* ln1_g = (const float*)d_in[7];
    const float* ln1_b = (const float*)d_in[8];
    const float* fc1_w = (const float*)d_in[9];
    const float* fc1_b = (const float*)d_in[10];
    const float* ln2_g = (const float*)d_in[11];
    const float* ln2_b = (const float*)d_in[12];
    const float* fc2_w = (const float*)d_in[13];
    const float* fc2_b = (const float*)d_in[14];
    const float* ln3_g = (const float*)d_in[15];
    const float* ln3_b = (const float*)d_in[16];
    const float* fc3_w = (const float*)d_in[17];
    const float* fc3_b = (const float*)d_in[18];
    const float* biases = (const float*)d_in[19];
    const int*  rel_idx = (const int*)d_in[20];

    half_t* wqkvT  = (half_t*)d_ws;
    half_t* wprojT = (half_t*)((char*)d_ws + 393216);
    float*  rbp    = (float*)((char*)d_ws + 524288);

    const int B = in_sizes[0] / (64 * 256);

    prep_kernel<<<65, 256, 0, stream>>>(qkv_w, proj_w, biases, pos_proj_w, pos_proj_b,
                                        ln1_g, ln1_b, fc1_w, fc1_b,
                                        ln2_g, ln2_b, fc2_w, fc2_b,
                                        ln3_g, ln3_b, fc3_w, fc3_b,
                                        rel_idx, wqkvT, wprojT, rbp);
    fused_kernel<<<B, 512, 0, stream>>>(x, wqkvT, qkv_b, wprojT, proj_b, rbp,
                                        (float*)d_out);
}